// Round 7
// baseline (191.792 us; speedup 1.0000x reference)
//
#include <hip/hip_runtime.h>
#include <stdint.h>

#define M_PIX 8192
#define N_CB  16384
#define KD    256

typedef float f32x4 __attribute__((ext_vector_type(4)));
typedef long long i64;
typedef unsigned long long ull;

// workspace layout (bytes)
#define OFF_CF8  (0ULL)            // codebook fp8 e4m3 : 16384*256 = 4 MB
#define OFF_XF8  (4ULL << 20)      // x fp8 e4m3        : 2 MB
#define OFF_CBSQ (6ULL << 20)      // ||c||^2 fp32      : 64 KB
#define OFF_SLOT (7ULL << 20)      // float2 top2/tile  : 128*8192*8 = 8 MB
#define WS_REQ   (15ULL << 20)

__device__ __forceinline__ unsigned int fkey(float s) {
  unsigned int f = __float_as_uint(s);
  return f ^ ((unsigned int)(((int)f) >> 31) | 0x80000000u);
}
// fp32 -> OCP e4m3fn, RNE, handles subnormals (step 2^-9), clamp 448
__device__ __forceinline__ unsigned char f2e4m3(float v) {
  float av = fminf(fabsf(v), 448.0f);
  const unsigned s = (__float_as_uint(v) >> 24) & 0x80u;
  unsigned m;
  if (av >= 0.015625f) {              // normal: round at mantissa bit 20
    unsigned u = __float_as_uint(av);
    u += 0x7FFFFu + ((u >> 20) & 1u);
    m = (((u >> 23) - 120u) << 3) | ((u >> 20) & 7u);
  } else {                            // subnormal
    m = (unsigned)(int)rintf(av * 512.0f);
  }
  return (unsigned char)(s | m);
}
__device__ __forceinline__ void gl_lds16(const unsigned char* g, char* l) {
  __builtin_amdgcn_global_load_lds(
      (const __attribute__((address_space(1))) unsigned int*)(const void*)g,
      (__attribute__((address_space(3))) unsigned int*)(void*)l,
      16, 0, 0);
}
// keep-smallest-2 on packed float keys: 3 VALU, no cndmask
__device__ __forceinline__ void ins2f(float k, float& v1, float& v2) {
  v2 = fminf(v2, fmaxf(v1, k));   // uses OLD v1
  v1 = fminf(v1, k);
}

// ---------------- kernel 1: fp32 -> fp8 e4m3 + codebook norms ---------------
__global__ __launch_bounds__(256) void prep_kernel(
    const float* __restrict__ x, const float* __restrict__ cb,
    unsigned char* __restrict__ Cf8, unsigned char* __restrict__ Xf8,
    float* __restrict__ cbsq) {
  const int wid = threadIdx.x >> 6, lane = threadIdx.x & 63;
  const int row = blockIdx.x * 4 + wid;        // grid = (N_CB+M_PIX)/4
  const bool isCb = (row < N_CB);
  const int rowL = isCb ? row : row - N_CB;
  const float* src = (isCb ? cb : x) + (size_t)rowL * KD;
  const float4 v = ((const float4*)src)[lane];
  const unsigned pk = (unsigned)f2e4m3(v.x) | ((unsigned)f2e4m3(v.y) << 8) |
                      ((unsigned)f2e4m3(v.z) << 16) | ((unsigned)f2e4m3(v.w) << 24);
  *(unsigned*)(void*)((isCb ? Cf8 : Xf8) + (size_t)rowL * KD + lane * 4) = pk;
  if (isCb) {
    float ss = v.x*v.x + v.y*v.y + v.z*v.z + v.w*v.w;   // fp32 norm
    #pragma unroll
    for (int off = 32; off > 0; off >>= 1) ss += __shfl_xor(ss, off);
    if (lane == 0) cbsq[rowL] = ss;
  }
}

// ---------------- kernel 2: fp8 GEMM + per-tile top-2 -----------------------
// s[p,n] = cbsq[n] - 2*(x8.c8); fp8 noise sigma ~0.8, near-min gap ~9 =>
// per-tile top-2 + k3 threshold(T=10) exact rescore. 8192 blocks / 4 waves
// (2x2, wave tile 64x64). K staged in two 128-col halves; A,B = 16 KB each.
// K-major LDS layout [8 groups][128 rows][16B]: frag addr = lane-base +
// kb*4096 (ds offset immediate) -> zero K-loop address VALU, no swizzle;
// row stride 16 B gives only inherent 2-way bank aliasing (free, m136).

__global__ __launch_bounds__(256, 4) void gemm_top2_kernel(
    const unsigned char* __restrict__ Xf8, const unsigned char* __restrict__ Cf8,
    const float* __restrict__ cbsq, float2* __restrict__ slots) {
  __shared__ __align__(16) char smem[32768];
  char* A_s = smem;                    // 16 KB: granule-group g at g*2048
  char* B_s = smem + 16384;           // 16 KB
  float* v1p = (float*)smem;           // epilogue overlay: 2 planes [128][32]
  float* v2p = (float*)(smem + 16384);

  const int tid = threadIdx.x;
  const int wid = tid >> 6, lane = tid & 63;
  const int wy = wid >> 1, wx = wid & 1;
  const int q = lane >> 4, c = lane & 15;

  // m-outer / n-inner per XCD: 16-block sweeps share one A-tile + B-strip
  const int bx = blockIdx.x & 7, bg = blockIdx.x >> 3;
  const int mt = bg >> 4;               // 0..63
  const int nt = bx * 16 + (bg & 15);   // 0..127
  const int m0 = mt * 128, n0 = nt * 128;

  // per-lane LDS frag bases (K-major): g = 2kb + (q>>1); kb part is immediate
  int abase[4], bbase[4];
  #pragma unroll
  for (int i = 0; i < 4; i++) {
    abase[i] = ((q >> 1) << 11) + (wy * 64 + i * 16 + c) * 16 + ((q & 1) << 3);
    bbase[i] = ((q >> 1) << 11) + (wx * 64 + i * 16 + c) * 16 + ((q & 1) << 3);
  }

  const f32x4 zf = {0.f, 0.f, 0.f, 0.f};
  f32x4 acc[4][4];
  #pragma unroll
  for (int i = 0; i < 4; i++)
    #pragma unroll
    for (int j = 0; j < 4; j++) acc[i][j] = zf;

  #pragma unroll
  for (int half = 0; half < 2; half++) {
    const int kc = half * 128;
    if (half) __syncthreads();          // prior half's frag reads done
    #pragma unroll
    for (int j = 0; j < 4; j++) {       // 1024 granules per operand-half
      const int s = j * 256 + tid;
      const int g = s >> 7, row = s & 127;   // g wave-uniform (64 | stride)
      const int lb = (j * 256 + (tid & 192)) * 16;   // wave-uniform LDS base
      gl_lds16(Xf8 + (size_t)(m0 + row) * KD + kc + g * 16, A_s + lb);
      gl_lds16(Cf8 + (size_t)(n0 + row) * KD + kc + g * 16, B_s + lb);
    }
    __syncthreads();
    #pragma unroll
    for (int kb = 0; kb < 4; kb++) {    // 4 x K=32 per half
      i64 bf[4];
      #pragma unroll
      for (int ni = 0; ni < 4; ni++)
        bf[ni] = *(const i64*)(const void*)(B_s + kb * 4096 + bbase[ni]);
      #pragma unroll
      for (int mi = 0; mi < 4; mi++) {
        const i64 af = *(const i64*)(const void*)(A_s + kb * 4096 + abase[mi]);
        #pragma unroll
        for (int ni = 0; ni < 4; ni++)
          acc[mi][ni] = __builtin_amdgcn_mfma_f32_16x16x32_fp8_fp8(af, bf[ni], acc[mi][ni], 0, 0, 0);
      }
    }
  }
  __syncthreads();   // tiles dead -> overlay planes

  float cs[4]; unsigned colp[4];
  #pragma unroll
  for (int ni = 0; ni < 4; ni++) {
    colp[ni] = wx * 64 + ni * 16 + c;
    cs[ni] = cbsq[n0 + colp[ni]];
  }
  const float FINF = __uint_as_float(0x7F800000u);

  // owner phase: C/D layout col=lane&15, row=q*4+reg (m89/m91); col packed
  // into low 7 mantissa bits (|err|<=0.008, absorbed by k3 threshold)
  #pragma unroll
  for (int mi = 0; mi < 4; mi++) {
    #pragma unroll
    for (int r = 0; r < 4; r++) {
      float v1 = FINF, v2 = FINF;
      #pragma unroll
      for (int ni = 0; ni < 4; ni++) {
        const float s = fmaf(-2.f, acc[mi][ni][r], cs[ni]);
        ins2f(__uint_as_float((__float_as_uint(s) & 0xFFFFFF80u) | colp[ni]),
              v1, v2);
      }
      const int row = wy * 64 + mi * 16 + q * 4 + r;
      const int slot = wx * 16 + c;
      const int off = row * 32 + ((((slot >> 2) ^ (row & 7))) << 2) + (slot & 3);
      v1p[off] = v1; v2p[off] = v2;
    }
  }
  __syncthreads();

  // scan: 2 threads/row, 16 pairs each, 1 shuffle merge, float2 store
  {
    const int srow = tid >> 1, half = tid & 1;
    float v1 = FINF, v2 = FINF;
    #pragma unroll
    for (int j = 0; j < 4; j++) {
      const int g = (half * 4 + j) ^ (srow & 7);
      const float4 a = *(const float4*)(const void*)(v1p + srow * 32 + g * 4);
      const float4 b = *(const float4*)(const void*)(v2p + srow * 32 + g * 4);
      ins2f(a.x, v1, v2); ins2f(a.y, v1, v2);
      ins2f(a.z, v1, v2); ins2f(a.w, v1, v2);
      ins2f(b.x, v1, v2); ins2f(b.y, v1, v2);
      ins2f(b.z, v1, v2); ins2f(b.w, v1, v2);
    }
    const float b1 = __shfl_xor(v1, 1), b2 = __shfl_xor(v2, 1);
    const float hi = fmaxf(v1, b1);
    v1 = fminf(v1, b1);
    v2 = fminf(fminf(v2, b2), hi);
    if (!half)
      slots[(size_t)nt * M_PIX + m0 + srow] = make_float2(v1, v2);
  }
}

// ---------------- kernel 3: global min + threshold exact rescore + gather ---
// Candidates with observed score < min+10 (6sigma_diff + pack err + margin)
// are rescored exactly in fp32; avg ~2 rescores/pixel.
__global__ __launch_bounds__(256) void reduce_rescore_gather(
    const float* __restrict__ x, const float* __restrict__ cb,
    const float* __restrict__ cbsq, const float2* __restrict__ slots,
    float* __restrict__ out) {
  const int wid = threadIdx.x >> 6, lane = threadIdx.x & 63;
  const int pixel = blockIdx.x * 4 + wid;     // grid = 8192/4

  const float2 sA = slots[(size_t)lane * M_PIX + pixel];
  const float2 sB = slots[(size_t)(64 + lane) * M_PIX + pixel];
  const float sc[4] = {sA.x, sA.y, sB.x, sB.y};
  float mn = fminf(fminf(sc[0], sc[1]), fminf(sc[2], sc[3]));
  #pragma unroll
  for (int off = 1; off < 64; off <<= 1) mn = fminf(mn, __shfl_xor(mn, off));
  const float thr = mn + 10.0f;

  const float4 xv = ((const float4*)x)[(size_t)pixel * 64 + lane];
  ull best = ~0ULL;
  #pragma unroll
  for (int j = 0; j < 4; j++) {
    ull mask = __ballot(sc[j] < thr);
    while (mask) {
      const int src = (int)__ffsll((long long)mask) - 1;
      mask &= mask - 1;
      const float val = __shfl(sc[j], src);
      const unsigned ij = (unsigned)(((j >> 1) * 64 + src) * 128) +
                          (__float_as_uint(val) & 127u);
      const float4 cv = ((const float4*)cb)[(size_t)ij * 64 + lane];
      float d = xv.x*cv.x + xv.y*cv.y + xv.z*cv.z + xv.w*cv.w;
      #pragma unroll
      for (int off = 1; off < 64; off <<= 1) d += __shfl_xor(d, off);
      const float sv = fmaf(-2.f, d, cbsq[ij]);
      const ull k = ((ull)fkey(sv) << 32) | ij;   // tie -> lowest idx (np)
      best = k < best ? k : best;
    }
  }
  const unsigned w = (unsigned)best;
  ((float4*)out)[(size_t)pixel * 64 + lane] = ((const float4*)cb)[(size_t)w * 64 + lane];
}

// ---------------- fallback (ws too small): exact fp32 scan ------------------
__global__ __launch_bounds__(256) void fallback_kernel(
    const float* __restrict__ x, const float* __restrict__ cb,
    float* __restrict__ out) {
  __shared__ float xs[256];
  __shared__ unsigned long long keys[4];
  __shared__ int widx;
  const int p = blockIdx.x;
  const int tid = threadIdx.x, wid = tid >> 6, lane = tid & 63;
  xs[tid] = x[(size_t)p * KD + tid];
  __syncthreads();
  const float4 xv = ((const float4*)xs)[lane];
  float bestS = 3.4e38f; int bestI = 0;
  for (int k = wid; k < N_CB; k += 4) {
    const float4 cv = ((const float4*)cb)[(size_t)k * 64 + lane];
    float t = cv.x*(cv.x - 2.f*xv.x) + cv.y*(cv.y - 2.f*xv.y)
            + cv.z*(cv.z - 2.f*xv.z) + cv.w*(cv.w - 2.f*xv.w);
    #pragma unroll
    for (int off = 1; off < 64; off <<= 1) t += __shfl_xor(t, off);
    if (t < bestS) { bestS = t; bestI = k; }
  }
  if (lane == 0)
    keys[wid] = ((unsigned long long)fkey(bestS) << 32) | (unsigned int)bestI;
  __syncthreads();
  if (tid == 0) {
    unsigned long long m = keys[0];
    for (int i = 1; i < 4; i++) if (keys[i] < m) m = keys[i];
    widx = (int)(unsigned int)(m & 0xFFFFFFFFULL);
  }
  __syncthreads();
  out[(size_t)p * KD + tid] = cb[(size_t)widx * KD + tid];
}

extern "C" void kernel_launch(void* const* d_in, const int* in_sizes, int n_in,
                              void* d_out, int out_size, void* d_ws, size_t ws_size,
                              hipStream_t stream) {
  const float* x  = (const float*)d_in[0];   // [8192,256]
  const float* cb = (const float*)d_in[1];   // [16384,256]
  float* out = (float*)d_out;                // [8192,256]

  if (ws_size < WS_REQ) {
    fallback_kernel<<<M_PIX, 256, 0, stream>>>(x, cb, out);
    return;
  }

  char* ws = (char*)d_ws;
  unsigned char* Cf8 = (unsigned char*)(ws + OFF_CF8);
  unsigned char* Xf8 = (unsigned char*)(ws + OFF_XF8);
  float* cbsq        = (float*)(ws + OFF_CBSQ);
  float2* slots      = (float2*)(ws + OFF_SLOT);

  prep_kernel<<<(N_CB + M_PIX) / 4, 256, 0, stream>>>(x, cb, Cf8, Xf8, cbsq);
  gemm_top2_kernel<<<M_PIX, 256, 0, stream>>>(Xf8, Cf8, cbsq, slots);
  reduce_rescore_gather<<<M_PIX / 4, 256, 0, stream>>>(x, cb, cbsq, slots, out);
}

// Round 8
// 154.679 us; speedup vs baseline: 1.2399x; 1.2399x over previous
//
#include <hip/hip_runtime.h>
#include <stdint.h>

#define M_PIX 8192
#define N_CB  16384
#define KD    256

typedef float f32x4 __attribute__((ext_vector_type(4)));
typedef long long ll2 __attribute__((ext_vector_type(2)));
typedef unsigned long long ull;

// workspace layout (bytes)
#define OFF_CF8  (0ULL)            // codebook fp8 e4m3 (permuted rows) : 4 MB
#define OFF_XF8  (4ULL << 20)      // x fp8 e4m3 (permuted rows)        : 2 MB
#define OFF_CBSQ (6ULL << 20)      // ||c||^2 fp32                      : 64 KB
#define OFF_SLOT (7ULL << 20)      // float2 top2 [tile][pixel]         : 8 MB
#define WS_REQ   (15ULL << 20)

__device__ __forceinline__ unsigned int fkey(float s) {
  unsigned int f = __float_as_uint(s);
  return f ^ ((unsigned int)(((int)f) >> 31) | 0x80000000u);
}
// fp32 -> OCP e4m3fn, RNE, handles subnormals (step 2^-9), clamp 448
__device__ __forceinline__ unsigned char f2e4m3(float v) {
  float av = fminf(fabsf(v), 448.0f);
  const unsigned s = (__float_as_uint(v) >> 24) & 0x80u;
  unsigned m;
  if (av >= 0.015625f) {              // normal: round at mantissa bit 20
    unsigned u = __float_as_uint(av);
    u += 0x7FFFFu + ((u >> 20) & 1u);
    m = (((u >> 23) - 120u) << 3) | ((u >> 20) & 7u);
  } else {                            // subnormal
    m = (unsigned)(int)rintf(av * 512.0f);
  }
  return (unsigned char)(s | m);
}
__device__ __forceinline__ void gl_lds16(const unsigned char* g, char* l) {
  __builtin_amdgcn_global_load_lds(
      (const __attribute__((address_space(1))) unsigned int*)(const void*)g,
      (__attribute__((address_space(3))) unsigned int*)(void*)l,
      16, 0, 0);
}
// keep-smallest-2 on packed float keys: 3 VALU, no cndmask
__device__ __forceinline__ void ins2f(float k, float& v1, float& v2) {
  v2 = fminf(v2, fmaxf(v1, k));   // uses OLD v1
  v1 = fminf(v1, k);
}

// ---------------- kernel 1: fp32 -> fp8 e4m3 permuted rows + cb norms -------
// Row permutation: element k (b7=half, b6-5=kb, b4-3=q, b2-0=j) stored at
// byte p = half<<7 | q<<5 | kb<<3 | j  (swap bits 3-4 <-> 5-6). This makes a
// single 16B LDS read = A/B frags for two consecutive k-steps.
__global__ __launch_bounds__(256) void prep_kernel(
    const float* __restrict__ x, const float* __restrict__ cb,
    unsigned char* __restrict__ Cf8, unsigned char* __restrict__ Xf8,
    float* __restrict__ cbsq) {
  const int wid = threadIdx.x >> 6, lane = threadIdx.x & 63;
  const int row = blockIdx.x * 4 + wid;        // grid = (N_CB+M_PIX)/4
  const bool isCb = (row < N_CB);
  const int rowL = isCb ? row : row - N_CB;
  const float* src = (isCb ? cb : x) + (size_t)rowL * KD;
  const float4 v = ((const float4*)src)[lane];
  const int k0 = lane * 4;
  const int p0 = (k0 & 0x87) | ((k0 & 0x18) << 2) | ((k0 >> 2) & 0x18);
  uchar4 pk;
  pk.x = f2e4m3(v.x); pk.y = f2e4m3(v.y); pk.z = f2e4m3(v.z); pk.w = f2e4m3(v.w);
  *(uchar4*)(void*)((isCb ? Cf8 : Xf8) + (size_t)rowL * KD + p0) = pk;
  if (isCb) {
    float ss = v.x*v.x + v.y*v.y + v.z*v.z + v.w*v.w;   // fp32 norm
    #pragma unroll
    for (int off = 32; off > 0; off >>= 1) ss += __shfl_xor(ss, off);
    if (lane == 0) cbsq[rowL] = ss;
  }
}

// ---------------- kernel 2: fp8 GEMM + per-tile top-2 -----------------------
// s[p,n] = cbsq[n] - 2*(x8.c8). 8192 blocks / 4 waves (2x2, wave tile 64x64).
// K staged in two 128-col halves; A,B = 16 KB each, LDS row stride 128 B
// (round-5 conflict-free shape). Frag read = ds_read_b128 at
// row*128 + q*32 + kp*16 (kp immediate): two k-steps per read, zero K-loop
// address VALU. Staging = identity-contiguous 1 KB chunks (coalesced).
// Epilogue planes [128][36] fp32 (padded, 16B-aligned) overlay the tiles.

__global__ __launch_bounds__(256, 4) void gemm_top2_kernel(
    const unsigned char* __restrict__ Xf8, const unsigned char* __restrict__ Cf8,
    const float* __restrict__ cbsq, float2* __restrict__ slots) {
  __shared__ __align__(16) char smem[36864];
  char* A_s = smem;                       // 16 KB [128][128B]
  char* B_s = smem + 16384;               // 16 KB
  float* v1p = (float*)smem;              // overlay: [128][36] = 18432 B
  float* v2p = (float*)(smem + 18432);    // overlay: [128][36]

  const int tid = threadIdx.x;
  const int wid = tid >> 6, lane = tid & 63;
  const int wy = wid >> 1, wx = wid & 1;
  const int q = lane >> 4, c = lane & 15;

  // m-outer / n-inner per XCD: 16-block sweeps share one A-tile + B-strip
  const int bx = blockIdx.x & 7, bg = blockIdx.x >> 3;
  const int mt = bg >> 4;               // 0..63
  const int nt = bx * 16 + (bg & 15);   // 0..127
  const int m0 = mt * 128, n0 = nt * 128;

  // per-lane LDS frag byte bases (within-half layout: row*128 + q*32 + kp*16)
  int abase[4], bbase[4];
  #pragma unroll
  for (int i = 0; i < 4; i++) {
    abase[i] = (wy * 64 + i * 16 + c) * 128 + q * 32;
    bbase[i] = (wx * 64 + i * 16 + c) * 128 + q * 32;
  }

  const f32x4 zf = {0.f, 0.f, 0.f, 0.f};
  f32x4 acc[4][4];
  #pragma unroll
  for (int i = 0; i < 4; i++)
    #pragma unroll
    for (int j = 0; j < 4; j++) acc[i][j] = zf;

  #pragma unroll
  for (int hk = 0; hk < 2; hk++) {        // two 128-col K-halves
    if (hk) __syncthreads();              // prior half's frag reads done
    #pragma unroll
    for (int j = 0; j < 4; j++) {         // 16 chunks of 1 KB per operand
      const int chunk = j * 4 + wid;      // wave-uniform
      const int row = chunk * 8 + (lane >> 3);
      const int gb = (lane & 7) * 16 + hk * 128;
      gl_lds16(Xf8 + (size_t)(m0 + row) * KD + gb, A_s + chunk * 1024);
      gl_lds16(Cf8 + (size_t)(n0 + row) * KD + gb, B_s + chunk * 1024);
    }
    __syncthreads();
    #pragma unroll
    for (int kp = 0; kp < 2; kp++) {      // kb-pairs; kp*16 is a ds immediate
      ll2 bfr[4];
      #pragma unroll
      for (int ni = 0; ni < 4; ni++)
        bfr[ni] = *(const ll2*)(const void*)(B_s + bbase[ni] + kp * 16);
      #pragma unroll
      for (int mi = 0; mi < 4; mi++) {
        const ll2 af = *(const ll2*)(const void*)(A_s + abase[mi] + kp * 16);
        #pragma unroll
        for (int ni = 0; ni < 4; ni++) {
          acc[mi][ni] = __builtin_amdgcn_mfma_f32_16x16x32_fp8_fp8(af.x, bfr[ni].x, acc[mi][ni], 0, 0, 0);
          acc[mi][ni] = __builtin_amdgcn_mfma_f32_16x16x32_fp8_fp8(af.y, bfr[ni].y, acc[mi][ni], 0, 0, 0);
        }
      }
    }
  }
  __syncthreads();   // tiles dead -> overlay planes

  float cs[4]; unsigned colp[4];
  #pragma unroll
  for (int ni = 0; ni < 4; ni++) {
    colp[ni] = wx * 64 + ni * 16 + c;
    cs[ni] = cbsq[n0 + colp[ni]];
  }
  const float FINF = __uint_as_float(0x7F800000u);

  // owner phase: C/D layout col=lane&15, row=q*4+reg (m89/m91); col packed
  // into low 7 mantissa bits (|err|<=0.008, absorbed by k3 threshold)
  #pragma unroll
  for (int mi = 0; mi < 4; mi++) {
    #pragma unroll
    for (int r = 0; r < 4; r++) {
      float v1 = FINF, v2 = FINF;
      #pragma unroll
      for (int ni = 0; ni < 4; ni++) {
        const float s = fmaf(-2.f, acc[mi][ni][r], cs[ni]);
        ins2f(__uint_as_float((__float_as_uint(s) & 0xFFFFFF80u) | colp[ni]),
              v1, v2);
      }
      const int row = wy * 64 + mi * 16 + q * 4 + r;
      const int slot = wx * 16 + c;
      v1p[row * 36 + slot] = v1;
      v2p[row * 36 + slot] = v2;
    }
  }
  __syncthreads();

  // scan: 2 threads/row over 16 partial-pairs each, 1 shuffle merge
  {
    const int srow = tid >> 1, half = tid & 1;
    float v1 = FINF, v2 = FINF;
    #pragma unroll
    for (int jj = 0; jj < 2; jj++) {
      const float4 a = *(const float4*)(const void*)(v1p + srow * 36 + half * 16 + jj * 8);
      const float4 a2 = *(const float4*)(const void*)(v1p + srow * 36 + half * 16 + jj * 8 + 4);
      const float4 b = *(const float4*)(const void*)(v2p + srow * 36 + half * 16 + jj * 8);
      const float4 b2 = *(const float4*)(const void*)(v2p + srow * 36 + half * 16 + jj * 8 + 4);
      ins2f(a.x, v1, v2);  ins2f(a.y, v1, v2);
      ins2f(a.z, v1, v2);  ins2f(a.w, v1, v2);
      ins2f(a2.x, v1, v2); ins2f(a2.y, v1, v2);
      ins2f(a2.z, v1, v2); ins2f(a2.w, v1, v2);
      ins2f(b.x, v1, v2);  ins2f(b.y, v1, v2);
      ins2f(b.z, v1, v2);  ins2f(b.w, v1, v2);
      ins2f(b2.x, v1, v2); ins2f(b2.y, v1, v2);
      ins2f(b2.z, v1, v2); ins2f(b2.w, v1, v2);
    }
    const float b1 = __shfl_xor(v1, 1), b2 = __shfl_xor(v2, 1);
    const float hi = fmaxf(v1, b1);
    v1 = fminf(v1, b1);
    v2 = fminf(fminf(v2, b2), hi);
    if (!half)
      slots[(size_t)nt * M_PIX + m0 + srow] = make_float2(v1, v2);
  }
}

// ---------------- kernel 3: global min + threshold exact rescore + gather ---
// Candidates with observed score < min+10 (noise + pack err + margin) are
// rescored exactly in fp32 (reads ORIGINAL fp32 cb rows); avg ~2 per pixel.
__global__ __launch_bounds__(256) void reduce_rescore_gather(
    const float* __restrict__ x, const float* __restrict__ cb,
    const float* __restrict__ cbsq, const float2* __restrict__ slots,
    float* __restrict__ out) {
  const int wid = threadIdx.x >> 6, lane = threadIdx.x & 63;
  const int pixel = blockIdx.x * 4 + wid;     // grid = 8192/4

  const float2 sA = slots[(size_t)lane * M_PIX + pixel];
  const float2 sB = slots[(size_t)(64 + lane) * M_PIX + pixel];
  const float sc[4] = {sA.x, sA.y, sB.x, sB.y};
  float mn = fminf(fminf(sc[0], sc[1]), fminf(sc[2], sc[3]));
  #pragma unroll
  for (int off = 1; off < 64; off <<= 1) mn = fminf(mn, __shfl_xor(mn, off));
  const float thr = mn + 10.0f;

  const float4 xv = ((const float4*)x)[(size_t)pixel * 64 + lane];
  ull best = ~0ULL;
  #pragma unroll
  for (int j = 0; j < 4; j++) {
    ull mask = __ballot(sc[j] < thr);
    while (mask) {
      const int src = (int)__ffsll((long long)mask) - 1;
      mask &= mask - 1;
      const float val = __shfl(sc[j], src);
      const unsigned ij = (unsigned)(((j >> 1) * 64 + src) * 128) +
                          (__float_as_uint(val) & 127u);
      const float4 cv = ((const float4*)cb)[(size_t)ij * 64 + lane];
      float d = xv.x*cv.x + xv.y*cv.y + xv.z*cv.z + xv.w*cv.w;
      #pragma unroll
      for (int off = 1; off < 64; off <<= 1) d += __shfl_xor(d, off);
      const float sv = fmaf(-2.f, d, cbsq[ij]);
      const ull k = ((ull)fkey(sv) << 32) | ij;   // tie -> lowest idx (np)
      best = k < best ? k : best;
    }
  }
  const unsigned w = (unsigned)best;
  ((float4*)out)[(size_t)pixel * 64 + lane] = ((const float4*)cb)[(size_t)w * 64 + lane];
}

// ---------------- fallback (ws too small): exact fp32 scan ------------------
__global__ __launch_bounds__(256) void fallback_kernel(
    const float* __restrict__ x, const float* __restrict__ cb,
    float* __restrict__ out) {
  __shared__ float xs[256];
  __shared__ unsigned long long keys[4];
  __shared__ int widx;
  const int p = blockIdx.x;
  const int tid = threadIdx.x, wid = tid >> 6, lane = tid & 63;
  xs[tid] = x[(size_t)p * KD + tid];
  __syncthreads();
  const float4 xv = ((const float4*)xs)[lane];
  float bestS = 3.4e38f; int bestI = 0;
  for (int k = wid; k < N_CB; k += 4) {
    const float4 cv = ((const float4*)cb)[(size_t)k * 64 + lane];
    float t = cv.x*(cv.x - 2.f*xv.x) + cv.y*(cv.y - 2.f*xv.y)
            + cv.z*(cv.z - 2.f*xv.z) + cv.w*(cv.w - 2.f*xv.w);
    #pragma unroll
    for (int off = 1; off < 64; off <<= 1) t += __shfl_xor(t, off);
    if (t < bestS) { bestS = t; bestI = k; }
  }
  if (lane == 0)
    keys[wid] = ((unsigned long long)fkey(bestS) << 32) | (unsigned int)bestI;
  __syncthreads();
  if (tid == 0) {
    unsigned long long m = keys[0];
    for (int i = 1; i < 4; i++) if (keys[i] < m) m = keys[i];
    widx = (int)(unsigned int)(m & 0xFFFFFFFFULL);
  }
  __syncthreads();
  out[(size_t)p * KD + tid] = cb[(size_t)widx * KD + tid];
}

extern "C" void kernel_launch(void* const* d_in, const int* in_sizes, int n_in,
                              void* d_out, int out_size, void* d_ws, size_t ws_size,
                              hipStream_t stream) {
  const float* x  = (const float*)d_in[0];   // [8192,256]
  const float* cb = (const float*)d_in[1];   // [16384,256]
  float* out = (float*)d_out;                // [8192,256]

  if (ws_size < WS_REQ) {
    fallback_kernel<<<M_PIX, 256, 0, stream>>>(x, cb, out);
    return;
  }

  char* ws = (char*)d_ws;
  unsigned char* Cf8 = (unsigned char*)(ws + OFF_CF8);
  unsigned char* Xf8 = (unsigned char*)(ws + OFF_XF8);
  float* cbsq        = (float*)(ws + OFF_CBSQ);
  float2* slots      = (float2*)(ws + OFF_SLOT);

  prep_kernel<<<(N_CB + M_PIX) / 4, 256, 0, stream>>>(x, cb, Cf8, Xf8, cbsq);
  gemm_top2_kernel<<<M_PIX, 256, 0, stream>>>(Xf8, Cf8, cbsq, slots);
  reduce_rescore_gather<<<M_PIX / 4, 256, 0, stream>>>(x, cb, cbsq, slots, out);
}